// Round 1
// baseline (721.442 us; speedup 1.0000x reference)
//
#include <hip/hip_runtime.h>
#include <math.h>

// E2M1 (MXFP4) block weight quantizer, block=32, layer_max=6.0.
// Outputs concatenated in d_out (float32):
//   [0, N)        deq_weight          N = 8192*8192
//   [N, 2N)       encoded (0..15 as float)
//   [2N, 2N+B)    e8m0_scale + 127    B = N/32
//   [2N+B, 2N+2B) eps_base = 0.5*tanh(eps_param)

constexpr long long OUT_F = 8192;
constexpr long long IN_F  = 8192;
constexpr long long NELEM = OUT_F * IN_F;      // 67108864
constexpr long long NBLK  = NELEM / 32;        // 2097152

__global__ __launch_bounds__(256) void e2m1_quant_kernel(
    const float* __restrict__ w,
    const float* __restrict__ eps_p,
    float* __restrict__ out)
{
    // 8 lanes per 32-elem block; each lane owns one float4 (4 elems).
    const long long tid  = (long long)blockIdx.x * blockDim.x + threadIdx.x;
    const long long b    = tid >> 3;          // block index [0, NBLK)
    const int       sub  = (int)(tid & 7);    // lane-in-block
    const long long base = b * 32 + (long long)sub * 4;

    const float4 wv = *reinterpret_cast<const float4*>(w + base);

    // block amax: per-lane max of 4, then butterfly over the aligned 8-lane group
    float a = fmaxf(fmaxf(fabsf(wv.x), fabsf(wv.y)),
                    fmaxf(fabsf(wv.z), fabsf(wv.w)));
    a = fmaxf(a, __shfl_xor(a, 1));
    a = fmaxf(a, __shfl_xor(a, 2));
    a = fmaxf(a, __shfl_xor(a, 4));

    // e8m0 = ceil(max(log2f32(amax/6), -127)); use double log2 -> float for a
    // correctly-rounded fp32 log2 (matches np.log2 float32; device log2f is
    // ~1ulp and a ceil-boundary flip would shift encoded by ~3).
    const float descale = a / 6.0f;                  // exact fp32 division, same as np
    float lf = (float)log2((double)descale);         // -inf if amax==0 -> clamped below
    lf = fmaxf(lf, -127.0f);
    const float e8 = ceilf(lf);
    const int   ei = (int)e8;
    const float rscale = ldexpf(1.0f, -ei);          // exact power of two

    // eps = 0.5 * tanh(p), correctly rounded to fp32 (matches np.tanh float32)
    const float ep = 0.5f * (float)tanh((double)eps_p[b]);

    const float vals[4] = {wv.x, wv.y, wv.z, wv.w};
    float deq[4], enc[4];

#pragma unroll
    for (int i = 0; i < 4; ++i) {
        const float wn = vals[i] * rscale;           // exact: mul by power of 2
        const float as = fmaxf(fabsf(wn) + ep, 0.0f);
        // threshold-count encode against E2M1 bounds
        const int o = (as > 0.25f) + (as > 0.75f) + (as > 1.25f) + (as > 1.75f)
                    + (as > 2.5f)  + (as > 3.5f)  + (as > 5.0f);
        // sign(w_norm)=+1 -> bit 0; zero or negative -> bit 1 (matches floor((2-sign)/2))
        const int sbit = (wn <= 0.0f) ? 1 : 0;
        // E2M1 value table {0,.5,1,1.5,2,3,4,6} computed arithmetically
        const float mant = (o < 2) ? (float)o * 0.5f
                                   : ldexpf(1.0f + (float)(o & 1) * 0.5f, (o >> 1) - 1);
        // mant * (+-1) * 2^ei is exact -> bitwise identical to reference deq
        const float sgn = sbit ? -1.0f : 1.0f;
        deq[i] = ldexpf(mant * sgn, ei);
        enc[i] = (float)(sbit * 8 + o);
    }

    // coalesced float4 stores
    *reinterpret_cast<float4*>(out + base) =
        make_float4(deq[0], deq[1], deq[2], deq[3]);
    *reinterpret_cast<float4*>(out + NELEM + base) =
        make_float4(enc[0], enc[1], enc[2], enc[3]);

    if (sub == 0) {
        out[2 * NELEM + b]        = e8 + 127.0f;  // e8m0_scale_uint8 as float
        out[2 * NELEM + NBLK + b] = ep;           // eps_base
    }
}

extern "C" void kernel_launch(void* const* d_in, const int* in_sizes, int n_in,
                              void* d_out, int out_size, void* d_ws, size_t ws_size,
                              hipStream_t stream) {
    const float* w     = (const float*)d_in[0];   // weight_fp  [8192*8192]
    const float* eps_p = (const float*)d_in[1];   // eps_param  [2097152]
    float* out = (float*)d_out;

    const long long n_threads = NELEM / 4;        // 16,777,216
    const int block = 256;
    const int grid  = (int)(n_threads / block);   // 65,536
    e2m1_quant_kernel<<<grid, block, 0, stream>>>(w, eps_p, out);
}

// Round 2
// 687.452 us; speedup vs baseline: 1.0494x; 1.0494x over previous
//
#include <hip/hip_runtime.h>
#include <math.h>

// E2M1 (MXFP4) block weight quantizer, block=32, layer_max=6.0.
// Outputs concatenated in d_out (float32):
//   [0, N)        deq_weight          N = 8192*8192
//   [N, 2N)       encoded (0..15 as float)
//   [2N, 2N+B)    e8m0_scale + 127    B = N/32
//   [2N+B, 2N+2B) eps_base = 0.5*tanh(eps_param)
//
// R2: all-fp32 math. R1 used fp64 log2/tanh (ocml fp64 paths) -> VALU/latency
// bound at 721us vs ~126us roofline. v_log_f32 (~1 ulp) worst case flips e8m0
// by 1 only when amax/6 is within 1 ulp of a power of two (<1 block in 2M
// expected), and that flip moves encoded by <=2 (< 2.46 threshold). tanh via
// hardware v_exp_f32: abs err ~1e-7, harmless at these thresholds.

constexpr long long OUT_F = 8192;
constexpr long long IN_F  = 8192;
constexpr long long NELEM = OUT_F * IN_F;      // 67108864
constexpr long long NBLK  = NELEM / 32;        // 2097152

__global__ __launch_bounds__(256) void e2m1_quant_kernel(
    const float* __restrict__ w,
    const float* __restrict__ eps_p,
    float* __restrict__ out)
{
    // 8 lanes per 32-elem block; each lane owns one float4 (4 elems).
    const long long tid  = (long long)blockIdx.x * blockDim.x + threadIdx.x;
    const long long b    = tid >> 3;          // block index [0, NBLK)
    const int       sub  = (int)(tid & 7);    // lane-in-block
    const long long base = b * 32 + (long long)sub * 4;

    const float4 wv = *reinterpret_cast<const float4*>(w + base);

    // block amax: per-lane max of 4, then butterfly over the aligned 8-lane group
    float a = fmaxf(fmaxf(fabsf(wv.x), fabsf(wv.y)),
                    fmaxf(fabsf(wv.z), fabsf(wv.w)));
    a = fmaxf(a, __shfl_xor(a, 1));
    a = fmaxf(a, __shfl_xor(a, 2));
    a = fmaxf(a, __shfl_xor(a, 4));

    // e8m0 = ceil(max(log2(amax/6), -127)) ; hardware v_log_f32 (~1 ulp).
    // log2(0) = -inf -> clamped to -127 by fmaxf.
    const float descale = a * (1.0f / 6.0f) ; // note: np does amax/6.0
    // Use true division to match np exactly at the ulp level (rcp would be 1ulp off):
    const float descale_div = a / 6.0f;
    float lf = __log2f(descale_div);
    (void)descale;
    lf = fmaxf(lf, -127.0f);
    const float e8 = ceilf(lf);
    const int   ei = (int)e8;
    const float rscale = ldexpf(1.0f, -ei);   // single v_ldexp_f32, exact pow2

    // eps = 0.5 * tanh(p) via hardware exp: tanh(t) = (1-e^-2t)/(1+e^-2t)
    const float p  = eps_p[b];
    const float t  = fabsf(p);
    const float em = __expf(-2.0f * t);       // in (0,1]
    const float th = (1.0f - em) / (1.0f + em);
    const float ep = 0.5f * copysignf(th, p);

    const float vals[4] = {wv.x, wv.y, wv.z, wv.w};
    float deq[4], enc[4];

#pragma unroll
    for (int i = 0; i < 4; ++i) {
        const float wn = vals[i] * rscale;    // exact: mul by power of 2
        const float as = fmaxf(fabsf(wn) + ep, 0.0f);
        // threshold-count encode against E2M1 bounds
        const int o = (as > 0.25f) + (as > 0.75f) + (as > 1.25f) + (as > 1.75f)
                    + (as > 2.5f)  + (as > 3.5f)  + (as > 5.0f);
        // sign(w_norm)=+1 -> 0; zero or negative -> 1 (matches floor((2-sign)/2))
        const int sbit = (wn <= 0.0f) ? 1 : 0;
        // E2M1 value table {0,.5,1,1.5,2,3,4,6} computed arithmetically
        const float mant = (o < 2) ? (float)o * 0.5f
                                   : ldexpf(1.0f + (float)(o & 1) * 0.5f, (o >> 1) - 1);
        const float sgn = sbit ? -1.0f : 1.0f;
        deq[i] = ldexpf(mant * sgn, ei);      // exact: <=3 sig bits * pow2
        enc[i] = (float)(sbit * 8 + o);
    }

    // coalesced float4 stores
    *reinterpret_cast<float4*>(out + base) =
        make_float4(deq[0], deq[1], deq[2], deq[3]);
    *reinterpret_cast<float4*>(out + NELEM + base) =
        make_float4(enc[0], enc[1], enc[2], enc[3]);

    if (sub == 0) {
        out[2 * NELEM + b]        = e8 + 127.0f;  // e8m0_scale_uint8 as float
        out[2 * NELEM + NBLK + b] = ep;           // eps_base
    }
}

extern "C" void kernel_launch(void* const* d_in, const int* in_sizes, int n_in,
                              void* d_out, int out_size, void* d_ws, size_t ws_size,
                              hipStream_t stream) {
    const float* w     = (const float*)d_in[0];   // weight_fp  [8192*8192]
    const float* eps_p = (const float*)d_in[1];   // eps_param  [2097152]
    float* out = (float*)d_out;

    const long long n_threads = NELEM / 4;        // 16,777,216
    const int block = 256;
    const int grid  = (int)(n_threads / block);   // 65,536
    e2m1_quant_kernel<<<grid, block, 0, stream>>>(w, eps_p, out);
}